// Round 5
// baseline (353.291 us; speedup 1.0000x reference)
//
#include <hip/hip_runtime.h>
#include <math.h>

// Problem constants (B=2, N=2048, C=1024, F=4096, H=16, D=64)
#define BN  4096
#define SEQ 2048
#define CH  1024
#define FF  4096
#define NH  16
#define HD  64

typedef short bf16x8 __attribute__((ext_vector_type(8)));
typedef float f32x4  __attribute__((ext_vector_type(4)));

#define MFMA16(a,b,c) __builtin_amdgcn_mfma_f32_16x16x32_bf16(a,b,c,0,0,0)

__device__ __forceinline__ unsigned short f2b(float f){
  unsigned u = __float_as_uint(f);
  u += 0x7fffu + ((u>>16)&1u);          // RNE to bf16
  return (unsigned short)(u>>16);
}

// pack two fp32 -> two bf16 (truncation) in ONE v_perm_b32
__device__ __forceinline__ unsigned pk2(float a, float b){
  return __builtin_amdgcn_perm(__float_as_uint(b), __float_as_uint(a), 0x07060302u);
}

#if __has_builtin(__builtin_amdgcn_exp2f)
__device__ __forceinline__ float fexp2(float x){ return __builtin_amdgcn_exp2f(x); }
#else
__device__ __forceinline__ float fexp2(float x){
  float r; asm("v_exp_f32 %0, %1" : "=v"(r) : "v"(x)); return r;
}
#endif

__device__ __forceinline__ void gl2lds16(const void* g, void* l){
  __builtin_amdgcn_global_load_lds(
      (__attribute__((address_space(1))) void*)g,
      (__attribute__((address_space(3))) void*)l, 16, 0, 0);
}

// bijective chunked XCD swizzle (T1): blocks with dispatch id d land on XCD
// d%8; remap so each XCD processes a CONTIGUOUS chunk of logical work ids.
// Requires nwg % 8 == 0 (all our grids satisfy this).
__device__ __forceinline__ unsigned xcd_chunk(unsigned id, unsigned nwg){
  const unsigned cpx = nwg >> 3;
  return (id & 7u)*cpx + (id >> 3);
}

// ---------------- transpose + fp32->bf16 convert (out[s][r] = in[r][s]*scale)
__global__ __launch_bounds__(256) void transpose_cvt(const float* __restrict__ in,
    unsigned short* __restrict__ out, int R, int S, float scale)
{
  __shared__ float tile[64][65];
  const int tid = threadIdx.x;
  const int tx = tid & 63, ty = tid >> 6;
  const int s0 = blockIdx.x * 64, r0 = blockIdx.y * 64;
  #pragma unroll
  for (int j = 0; j < 16; j++){
    int r = ty + j*4;
    tile[r][tx] = in[(size_t)(r0 + r)*S + s0 + tx];
  }
  __syncthreads();
  #pragma unroll
  for (int j = 0; j < 16; j++){
    int s = ty + j*4;
    out[(size_t)(s0 + s)*R + r0 + tx] = f2b(tile[tx][s] * scale);
  }
}

// ---------------- LayerNorm (fp32 in, bf16 out), one block per row of 1024
__global__ __launch_bounds__(256) void ln_kernel(const float* __restrict__ x,
    const float* __restrict__ gamma, const float* __restrict__ beta,
    unsigned short* __restrict__ out)
{
  const int row = blockIdx.x, tid = threadIdx.x;
  const float4 xv = ((const float4*)(x + (size_t)row*CH))[tid];
  float s  = xv.x + xv.y + xv.z + xv.w;
  float ss = xv.x*xv.x + xv.y*xv.y + xv.z*xv.z + xv.w*xv.w;
  #pragma unroll
  for (int off = 1; off < 64; off <<= 1){
    s  += __shfl_xor(s,  off, 64);
    ss += __shfl_xor(ss, off, 64);
  }
  __shared__ float red[8];
  const int w = tid >> 6;
  if ((tid & 63) == 0){ red[w] = s; red[4+w] = ss; }
  __syncthreads();
  s  = red[0]+red[1]+red[2]+red[3];
  ss = red[4]+red[5]+red[6]+red[7];
  const float mu   = s * (1.f/CH);
  const float rstd = rsqrtf(ss*(1.f/CH) - mu*mu + 1e-6f);
  const float4 g = ((const float4*)gamma)[tid];
  const float4 b = ((const float4*)beta )[tid];
  ushort4 o;
  o.x = f2b((xv.x-mu)*rstd*g.x + b.x);
  o.y = f2b((xv.y-mu)*rstd*g.y + b.y);
  o.z = f2b((xv.z-mu)*rstd*g.z + b.z);
  o.w = f2b((xv.w-mu)*rstd*g.w + b.w);
  ((ushort4*)(out + (size_t)row*CH))[tid] = o;
}

// ---------------- gemm_p: pipelined GEMM, C = A[M,K] * Bt[Nn,K]^T, bf16->fp32
// BNT=128: 128x128 tile, 4 waves 2x2 (64x64 each).  BNT=64: 128x64 tile,
// 4 waves stacked in M (32x64 each).  BK=32.
// T3/T4 pipeline: 3 LDS buffers, prefetch 2 iterations ahead; end-of-iter
// sync = sched_barrier; s_waitcnt vmcnt(LPS) [NOT 0 - current stage stays in
// flight]; s_barrier; sched_barrier.  Each load gets ~2 compute phases of
// latency cover.  WAR on buffer (t+2)%3==(t-1)%3 is safe: iter t-1's barrier
// orders all reads before iter t's stage issues.  Tail drains vmcnt(0).
// LDS swizzle for 64B rows: slot s of row r holds 16B chunk s^((r>>1)&3);
// ds_read_b128 per 16 rows -> exactly 2-way bank aliasing (free, m136).
// OMODE: 0 = fp32 out, 1 = bf16 out, 3 = fused QKV epilogue (q/k token-major,
// v pi-permuted transposed).  OMODE 1/3 stage wave's bf16 tile in LDS scratch
// then store coalesced 16B.
template<int BNT,int BIAS,int GELU,int RES,int OMODE>
__global__ __launch_bounds__(256,4) void gemm_p(const unsigned short* __restrict__ A,
    const unsigned short* __restrict__ Bt, const float* __restrict__ bias,
    const float* __restrict__ resid, float* __restrict__ outF,
    unsigned short* __restrict__ outB, unsigned short* __restrict__ outK,
    unsigned short* __restrict__ outV, int M, int Nn, int K)
{
  constexpr int MI   = (BNT==128) ? 4 : 2;
  constexpr int ABUF = 8192;                 // 128 rows x 32 cols x 2B
  constexpr int BBUF = BNT*64;               // BNT rows x 32 cols x 2B
  constexpr int BUFB = ABUF + BBUF;
  __shared__ __align__(16) char lds[3*BUFB];
  const int tid = threadIdx.x;
  const int w = tid >> 6, lane = tid & 63;
  const int quad = lane >> 4, l16 = lane & 15;
  const unsigned Wid = xcd_chunk(blockIdx.y*gridDim.x + blockIdx.x,
                                 gridDim.x*gridDim.y);
  const int bx = Wid % gridDim.x, by = Wid / gridDim.x;
  const int m0 = by*128, n0 = bx*BNT;
  const int wm = (BNT==128) ? (w >> 1)*64 : w*32;
  const int wn = (BNT==128) ? (w & 1)*64 : 0;
  f32x4 acc[MI][4] = {};
  const int nt = K >> 5;

  // staging: 1KB chunks (16 rows x 32 elems); A has 8 chunks, B has BNT/16.
  // wave w: A chunks {2w,2w+1}; B chunks {2w,2w+1} (BNT=128) or {w} (BNT=64).
  const int ci0 = w*2, ci1 = w*2 + 1;
  const int ra0 = ci0*16 + (lane >> 2);
  const int ra1 = ra0 + 16;
  const int ga0 = (lane & 3) ^ ((ra0 >> 1) & 3);
  const int ga1 = (lane & 3) ^ ((ra1 >> 1) & 3);
  const unsigned short* aS0 = A + (size_t)(m0 + ra0)*K + ga0*8;
  const unsigned short* aS1 = A + (size_t)(m0 + ra1)*K + ga1*8;
  const int rb0 = (BNT==128) ? ra0 : (w*16 + (lane >> 2));
  const int gb0 = (lane & 3) ^ ((rb0 >> 1) & 3);
  const unsigned short* bS0 = Bt + (size_t)(n0 + rb0)*K + gb0*8;
  const unsigned short* bS1 = Bt + (size_t)(n0 + ra1)*K + ga1*8;  // BNT=128 only

  auto STAGE = [&](int buf){
    char* Ad = lds + buf*BUFB;
    char* Bd = Ad + ABUF;
    gl2lds16(aS0, Ad + ci0*1024);
    gl2lds16(aS1, Ad + ci1*1024);
    if (BNT == 128){
      gl2lds16(bS0, Bd + ci0*1024);
      gl2lds16(bS1, Bd + ci1*1024);
    } else {
      gl2lds16(bS0, Bd + w*1024);
    }
    aS0 += 32; aS1 += 32; bS0 += 32; bS1 += 32;
  };

  // prologue: stage tiles 0,1; wait tile 0 landed (tile 1 stays in flight)
  STAGE(0); STAGE(1);
  if (BNT == 128) asm volatile("s_waitcnt vmcnt(4)" ::: "memory");
  else            asm volatile("s_waitcnt vmcnt(3)" ::: "memory");
  __builtin_amdgcn_s_barrier();
  __builtin_amdgcn_sched_barrier(0);

  int bufR = 0, bufW = 2;
  for (int t = 0; t < nt; t++){
    const bool more = (t + 2 < nt);
    if (more){ STAGE(bufW); bufW = (bufW == 2) ? 0 : bufW + 1; }
    const unsigned short* Ac = (const unsigned short*)(lds + bufR*BUFB);
    const unsigned short* Bc = (const unsigned short*)(lds + bufR*BUFB + ABUF);
    bf16x8 af[MI], bfr[4];
    #pragma unroll
    for (int mi = 0; mi < MI; mi++){
      const int r = wm + mi*16 + l16;
      af[mi] = *(const bf16x8*)(Ac + r*32 + ((quad ^ ((r >> 1) & 3))*8));
    }
    #pragma unroll
    for (int nj = 0; nj < 4; nj++){
      const int r = wn + nj*16 + l16;
      bfr[nj] = *(const bf16x8*)(Bc + r*32 + ((quad ^ ((r >> 1) & 3))*8));
    }
    #pragma unroll
    for (int mi = 0; mi < MI; mi++)
      #pragma unroll
      for (int nj = 0; nj < 4; nj++)
        acc[mi][nj] = MFMA16(af[mi], bfr[nj], acc[mi][nj]);
    __builtin_amdgcn_sched_barrier(0);
    if (more){
      if (BNT == 128) asm volatile("s_waitcnt vmcnt(4)" ::: "memory");
      else            asm volatile("s_waitcnt vmcnt(3)" ::: "memory");
    } else {
      asm volatile("s_waitcnt vmcnt(0)" ::: "memory");
    }
    __builtin_amdgcn_s_barrier();
    __builtin_amdgcn_sched_barrier(0);
    bufR = (bufR == 2) ? 0 : bufR + 1;
  }

  // epilogue: C/D layout col = l16, row = quad*4 + reg
  const int colb = n0 + wn;          // 64-aligned
  const int row0 = m0 + wm;
  if (OMODE == 1 || OMODE == 3){
    unsigned short* scr = (unsigned short*)lds + w*4096;   // 8KB per wave
    const int cg = (OMODE == 3) ? (colb >> 10) : 0;
    #pragma unroll
    for (int nj = 0; nj < 4; nj++){
      const int col = colb + nj*16 + l16;
      const float bv = BIAS ? bias[col] : 0.f;
      #pragma unroll
      for (int mi = 0; mi < MI; mi++){
        #pragma unroll
        for (int r = 0; r < 4; r++){
          const int rl = mi*16 + quad*4 + r;     // local row
          float v = acc[mi][nj][r] + bv;
          if (GELU) v = 0.5f*v*(1.f + erff(v*0.70710678118654752f));
          if (RES)  v += resid[(size_t)(row0 + rl)*Nn + col];
          const unsigned short b16 = f2b(v);
          if (OMODE == 3 && cg == 2){
            // V: scratch [64 d][64 tok], tokens pi-permuted
            const int d = nj*16 + l16;
            scr[d*64 + (((rl & 15) << 2) | (rl >> 4))] = b16;
          } else {
            scr[rl*64 + nj*16 + l16] = b16;
          }
        }
      }
    }
    const int sl = (lane & 7)*8;
    #pragma unroll
    for (int j = 0; j < 8; j++){
      const int rr = j*8 + (lane >> 3);
      const bf16x8 vv = *(const bf16x8*)(scr + rr*64 + sl);
      if (OMODE == 1){
        *(bf16x8*)(outB + (size_t)(row0 + rr)*Nn + colb + sl) = vv;
      } else {
        if (cg == 0)
          *(bf16x8*)(outB + (size_t)(row0 + rr)*CH + (colb & (CH-1)) + sl) = vv;
        else if (cg == 1)
          *(bf16x8*)(outK + (size_t)(row0 + rr)*CH + (colb & (CH-1)) + sl) = vv;
        else {
          const int bb = row0 >> 11;
          const int hh = (colb & (CH-1)) >> 6;
          *(bf16x8*)(outV + ((size_t)((bb*NH + hh)*HD) + rr)*SEQ
                          + (row0 & (SEQ-1)) + sl) = vv;
        }
      }
    }
    return;
  }
  // OMODE 0: fp32 direct
  #pragma unroll
  for (int nj = 0; nj < 4; nj++){
    const int col = colb + nj*16 + l16;
    const float bv = BIAS ? bias[col] : 0.f;
    #pragma unroll
    for (int mi = 0; mi < MI; mi++){
      #pragma unroll
      for (int r = 0; r < 4; r++){
        const int row = row0 + mi*16 + quad*4 + r;
        float v = acc[mi][nj][r] + bv;
        if (GELU) v = 0.5f*v*(1.f + erff(v*0.70710678118654752f));
        if (RES)  v += resid[(size_t)row*Nn + col];
        outF[(size_t)row*Nn + col] = v;
      }
    }
  }
}

// ---------------- fused attention, no-max softmax (scores tiny; log2e folded into Wq)
// q,k token-major bf16; vt [bh][d][kv-pi-permuted] bf16.
// Block = one (b,h) x 128 Q rows; 4 waves = (wq: q-half of 64 rows) x (wk: kv-half).
// Grid XCD-chunk-swizzled: each XCD owns 4 heads (2MB K+V, L2-resident).
__global__ __launch_bounds__(256,2) void attn_kernel(const unsigned short* __restrict__ q,
    const unsigned short* __restrict__ k, const unsigned short* __restrict__ vt,
    unsigned short* __restrict__ y)
{
  __shared__ __align__(16) unsigned short Kl[2][64*64];
  __shared__ __align__(16) unsigned short Vl[2][64*64];
  __shared__ __align__(16) unsigned short Pp[4][64*68];
  const int tid = threadIdx.x;
  const int w = tid >> 6, lane = tid & 63;
  const int wq = w & 1, wk = w >> 1;
  const int quad = lane >> 4, l16 = lane & 15;
  const unsigned Wid = xcd_chunk(blockIdx.y*gridDim.x + blockIdx.x,
                                 gridDim.x*gridDim.y);
  const int qt = Wid & 15, bh = Wid >> 4;
  const int b = bh >> 4, h = bh & 15;
  const size_t tb  = ((size_t)b*SEQ)*CH + h*HD;
  const size_t vb_ = (size_t)bh*HD*SEQ;
  const int qr0 = qt*128 + wq*64;

  bf16x8 qf[4][2];
  #pragma unroll
  for (int mi = 0; mi < 4; mi++)
    #pragma unroll
    for (int kc = 0; kc < 2; kc++)
      qf[mi][kc] = *(const bf16x8*)(q + tb + (size_t)(qr0 + mi*16 + l16)*CH + kc*32 + quad*8);

  float sacc[4][4];
  f32x4 o[4][4] = {};
  #pragma unroll
  for (int mi = 0; mi < 4; mi++)
    #pragma unroll
    for (int r = 0; r < 4; r++) sacc[mi][r] = 0.f;

  for (int t = 0; t < 16; t++){
    const int kv0 = wk*1024 + t*64;
    __syncthreads();
    #pragma unroll
    for (int i = 0; i < 8; i++){
      const int r = i*8 + (lane >> 3);
      const int c = (lane & 7) ^ (r & 7);
      if (wq == 0)
        gl2lds16(k  + tb  + (size_t)(kv0 + r)*CH + c*8, (char*)&Kl[wk][0] + i*1024);
      else
        gl2lds16(vt + vb_ + (size_t)r*SEQ + kv0 + c*8, (char*)&Vl[wk][0] + i*1024);
    }
    __syncthreads();

    f32x4 s[4][4] = {};
    #pragma unroll
    for (int kc = 0; kc < 2; kc++){
      #pragma unroll
      for (int nj = 0; nj < 4; nj++){
        bf16x8 kf = *(const bf16x8*)(&Kl[wk][0] + (nj*16 + l16)*64 + (((kc*4 + quad) ^ (l16 & 7))*8));
        #pragma unroll
        for (int mi = 0; mi < 4; mi++)
          s[mi][nj] = MFMA16(qf[mi][kc], kf, s[mi][nj]);
      }
    }
    #pragma unroll
    for (int mi = 0; mi < 4; mi++){
      #pragma unroll
      for (int r = 0; r < 4; r++){
        const float p0 = fexp2(s[mi][0][r]);
        const float p1 = fexp2(s[mi][1][r]);
        const float p2 = fexp2(s[mi][2][r]);
        const float p3 = fexp2(s[mi][3][r]);
        sacc[mi][r] += (p0 + p1) + (p2 + p3);
        uint2 pk;
        pk.x = pk2(p0, p1);
        pk.y = pk2(p2, p3);
        const int prow = mi*16 + quad*4 + r;
        *(uint2*)(&Pp[w][prow*68 + l16*4]) = pk;
      }
    }
    #pragma unroll
    for (int kc = 0; kc < 2; kc++){
      bf16x8 pa[4];
      #pragma unroll
      for (int mi = 0; mi < 4; mi++)
        pa[mi] = *(const bf16x8*)(&Pp[w][(mi*16 + l16)*68 + kc*32 + quad*8]);
      #pragma unroll
      for (int nd = 0; nd < 4; nd++){
        bf16x8 vf = *(const bf16x8*)(&Vl[wk][0] + (nd*16 + l16)*64 + (((kc*4 + quad) ^ (l16 & 7))*8));
        #pragma unroll
        for (int mi = 0; mi < 4; mi++)
          o[mi][nd] = MFMA16(pa[mi], vf, o[mi][nd]);
      }
    }
  }

  __syncthreads();
  float* ob = wq ? (float*)&Vl[0][0] : (float*)&Kl[0][0];
  float* sb = (float*)&Pp[2 + wq][0];
  if (wk == 1){
    #pragma unroll
    for (int mi = 0; mi < 4; mi++)
      #pragma unroll
      for (int nd = 0; nd < 4; nd++)
        #pragma unroll
        for (int r = 0; r < 4; r++){
          const int idx = (mi*4 + nd)*4 + r;
          ob[lane*64 + ((idx + lane) & 63)] = o[mi][nd][r];
        }
    #pragma unroll
    for (int mi = 0; mi < 4; mi++)
      #pragma unroll
      for (int r = 0; r < 4; r++)
        sb[lane*16 + ((mi*4 + r + lane) & 15)] = sacc[mi][r];
  }
  __syncthreads();
  if (wk == 0){
    #pragma unroll
    for (int mi = 0; mi < 4; mi++)
      #pragma unroll
      for (int nd = 0; nd < 4; nd++)
        #pragma unroll
        for (int r = 0; r < 4; r++){
          const int idx = (mi*4 + nd)*4 + r;
          o[mi][nd][r] += ob[lane*64 + ((idx + lane) & 63)];
        }
    #pragma unroll
    for (int mi = 0; mi < 4; mi++){
      #pragma unroll
      for (int r = 0; r < 4; r++){
        float sum = sacc[mi][r] + sb[lane*16 + ((mi*4 + r + lane) & 15)];
        #pragma unroll
        for (int off = 1; off < 16; off <<= 1) sum += __shfl_xor(sum, off, 64);
        const float inv = 1.f / sum;
        const int qr = qr0 + mi*16 + quad*4 + r;
        #pragma unroll
        for (int nd = 0; nd < 4; nd++)
          y[tb + (size_t)qr*CH + nd*16 + l16] = f2b(o[mi][nd][r]*inv);
      }
    }
  }
}

extern "C" void kernel_launch(void* const* d_in, const int* in_sizes, int n_in,
                              void* d_out, int out_size, void* d_ws, size_t ws_size,
                              hipStream_t stream)
{
  (void)in_sizes; (void)n_in; (void)out_size; (void)ws_size;
  const float* x   = (const float*)d_in[0];
  const float* Wq  = (const float*)d_in[1];
  const float* Wk  = (const float*)d_in[2];
  const float* Wv  = (const float*)d_in[3];
  const float* Wp  = (const float*)d_in[4];
  const float* bp  = (const float*)d_in[5];
  const float* W1  = (const float*)d_in[6];
  const float* b1  = (const float*)d_in[7];
  const float* W2  = (const float*)d_in[8];
  const float* b2  = (const float*)d_in[9];
  const float* g1  = (const float*)d_in[10];
  const float* be1 = (const float*)d_in[11];
  const float* g2  = (const float*)d_in[12];
  const float* be2 = (const float*)d_in[13];
  float* out = (float*)d_out;
  char* ws = (char*)d_ws;
  const size_t MB = 1024*1024;
  unsigned short* wq_t = (unsigned short*)(ws +  0*MB);  // stacked QKV^T: rows 0..3071
  unsigned short* wk_t = (unsigned short*)(ws +  2*MB);
  unsigned short* wv_t = (unsigned short*)(ws +  4*MB);
  unsigned short* wp_t = (unsigned short*)(ws +  6*MB);
  unsigned short* w1_t = (unsigned short*)(ws +  8*MB);
  unsigned short* w2_t = (unsigned short*)(ws + 16*MB);
  unsigned short* xn   = (unsigned short*)(ws + 24*MB);
  unsigned short* qb   = (unsigned short*)(ws + 32*MB);
  unsigned short* kb   = (unsigned short*)(ws + 40*MB);
  unsigned short* vtb  = (unsigned short*)(ws + 48*MB);
  unsigned short* yb   = (unsigned short*)(ws + 56*MB);
  float*          x2   = (float*)         (ws + 64*MB);
  unsigned short* xn2  = (unsigned short*)(ws + 80*MB);
  unsigned short* hb   = (unsigned short*)(ws + 88*MB);

  // weight transposes to B^T bf16 (head scale * log2e folded into Wq)
  transpose_cvt<<<dim3(16,16),256,0,stream>>>(Wq, wq_t, CH, CH, 0.18033688011112042f);
  transpose_cvt<<<dim3(16,16),256,0,stream>>>(Wk, wk_t, CH, CH, 1.f);
  transpose_cvt<<<dim3(16,16),256,0,stream>>>(Wv, wv_t, CH, CH, 1.f);
  transpose_cvt<<<dim3(16,16),256,0,stream>>>(Wp, wp_t, CH, CH, 1.f);
  transpose_cvt<<<dim3(64,16),256,0,stream>>>(W1, w1_t, CH, FF, 1.f);
  transpose_cvt<<<dim3(16,64),256,0,stream>>>(W2, w2_t, FF, CH, 1.f);

  ln_kernel<<<BN,256,0,stream>>>(x, g1, be1, xn);
  // fused QKV: Bt = stacked [3072][1024] starting at wq_t
  gemm_p<128,0,0,0,3><<<dim3(24,32),256,0,stream>>>(xn, wq_t, nullptr, nullptr,
      nullptr, qb, kb, vtb, BN, 3072, CH);
  attn_kernel<<<dim3(16,32),256,0,stream>>>(qb, kb, vtb, yb);
  gemm_p<64,1,0,1,0><<<dim3(16,32),256,0,stream>>>(yb, wp_t, bp, x, x2,
      nullptr, nullptr, nullptr, BN, CH, CH);
  ln_kernel<<<BN,256,0,stream>>>(x2, g2, be2, xn2);
  gemm_p<128,1,1,0,1><<<dim3(32,32),256,0,stream>>>(xn2, w1_t, b1, nullptr, nullptr,
      hb, nullptr, nullptr, BN, FF, CH);
  // W2: single pass (no split-K, no memset, no atomics)
  gemm_p<64,1,0,1,0><<<dim3(16,32),256,0,stream>>>(hb, w2_t, b2, x2, out,
      nullptr, nullptr, nullptr, BN, CH, FF);
}

// Round 6
// 325.302 us; speedup vs baseline: 1.0860x; 1.0860x over previous
//
#include <hip/hip_runtime.h>
#include <math.h>

// Problem constants (B=2, N=2048, C=1024, F=4096, H=16, D=64)
#define BN  4096
#define SEQ 2048
#define CH  1024
#define FF  4096
#define NH  16
#define HD  64

typedef short bf16x8 __attribute__((ext_vector_type(8)));
typedef float f32x4  __attribute__((ext_vector_type(4)));

#define MFMA16(a,b,c) __builtin_amdgcn_mfma_f32_16x16x32_bf16(a,b,c,0,0,0)

__device__ __forceinline__ unsigned short f2b(float f){
  unsigned u = __float_as_uint(f);
  u += 0x7fffu + ((u>>16)&1u);          // RNE to bf16
  return (unsigned short)(u>>16);
}

// pack two fp32 -> two bf16 (truncation) in ONE v_perm_b32
__device__ __forceinline__ unsigned pk2(float a, float b){
  return __builtin_amdgcn_perm(__float_as_uint(b), __float_as_uint(a), 0x07060302u);
}

#if __has_builtin(__builtin_amdgcn_exp2f)
__device__ __forceinline__ float fexp2(float x){ return __builtin_amdgcn_exp2f(x); }
#else
__device__ __forceinline__ float fexp2(float x){
  float r; asm("v_exp_f32 %0, %1" : "=v"(r) : "v"(x)); return r;
}
#endif

__device__ __forceinline__ void gl2lds16(const void* g, void* l){
  __builtin_amdgcn_global_load_lds(
      (__attribute__((address_space(1))) void*)g,
      (__attribute__((address_space(3))) void*)l, 16, 0, 0);
}

// bijective chunked XCD swizzle (T1): blocks with dispatch id d land on XCD
// d%8; remap so each XCD processes a CONTIGUOUS chunk of logical work ids.
// Requires nwg % 8 == 0 (all our grids satisfy this).
__device__ __forceinline__ unsigned xcd_chunk(unsigned id, unsigned nwg){
  const unsigned cpx = nwg >> 3;
  return (id & 7u)*cpx + (id >> 3);
}

// ---------------- fused weight transposes: one launch for all six
// (out[s][r] = in[r][s]*scale).  Block demux by linear id:
// [0,256)Wq [256,512)Wk [512,768)Wv [768,1024)Wp [1024,2048)W1 [2048,3072)W2
__global__ __launch_bounds__(256) void transpose_all(
    const float* __restrict__ Wq, const float* __restrict__ Wk,
    const float* __restrict__ Wv, const float* __restrict__ Wp,
    const float* __restrict__ W1, const float* __restrict__ W2,
    unsigned short* __restrict__ wq_t, unsigned short* __restrict__ wk_t,
    unsigned short* __restrict__ wv_t, unsigned short* __restrict__ wp_t,
    unsigned short* __restrict__ w1_t, unsigned short* __restrict__ w2_t)
{
  const int id = blockIdx.x;
  const float* in; unsigned short* out; int R, S, bx, by; float scale = 1.f;
  if (id < 1024){
    const int which = id >> 8, t = id & 255;
    bx = t & 15; by = t >> 4; R = 1024; S = 1024;
    if (which == 0){ in = Wq; out = wq_t; scale = 0.18033688011112042f; }
    else if (which == 1){ in = Wk; out = wk_t; }
    else if (which == 2){ in = Wv; out = wv_t; }
    else               { in = Wp; out = wp_t; }
  } else if (id < 2048){
    const int t = id - 1024; bx = t & 63; by = t >> 6;
    R = 1024; S = 4096; in = W1; out = w1_t;
  } else {
    const int t = id - 2048; bx = t & 15; by = t >> 4;
    R = 4096; S = 1024; in = W2; out = w2_t;
  }
  __shared__ float tile[64][65];
  const int tid = threadIdx.x;
  const int tx = tid & 63, ty = tid >> 6;
  const int s0 = bx * 64, r0 = by * 64;
  #pragma unroll
  for (int j = 0; j < 16; j++){
    int r = ty + j*4;
    tile[r][tx] = in[(size_t)(r0 + r)*S + s0 + tx];
  }
  __syncthreads();
  #pragma unroll
  for (int j = 0; j < 16; j++){
    int s = ty + j*4;
    out[(size_t)(s0 + s)*R + r0 + tx] = f2b(tile[tx][s] * scale);
  }
}

// ---------------- LayerNorm (fp32 in, bf16 out), one block per row of 1024
__global__ __launch_bounds__(256) void ln_kernel(const float* __restrict__ x,
    const float* __restrict__ gamma, const float* __restrict__ beta,
    unsigned short* __restrict__ out)
{
  const int row = blockIdx.x, tid = threadIdx.x;
  const float4 xv = ((const float4*)(x + (size_t)row*CH))[tid];
  float s  = xv.x + xv.y + xv.z + xv.w;
  float ss = xv.x*xv.x + xv.y*xv.y + xv.z*xv.z + xv.w*xv.w;
  #pragma unroll
  for (int off = 1; off < 64; off <<= 1){
    s  += __shfl_xor(s,  off, 64);
    ss += __shfl_xor(ss, off, 64);
  }
  __shared__ float red[8];
  const int w = tid >> 6;
  if ((tid & 63) == 0){ red[w] = s; red[4+w] = ss; }
  __syncthreads();
  s  = red[0]+red[1]+red[2]+red[3];
  ss = red[4]+red[5]+red[6]+red[7];
  const float mu   = s * (1.f/CH);
  const float rstd = rsqrtf(ss*(1.f/CH) - mu*mu + 1e-6f);
  const float4 g = ((const float4*)gamma)[tid];
  const float4 b = ((const float4*)beta )[tid];
  ushort4 o;
  o.x = f2b((xv.x-mu)*rstd*g.x + b.x);
  o.y = f2b((xv.y-mu)*rstd*g.y + b.y);
  o.z = f2b((xv.z-mu)*rstd*g.z + b.z);
  o.w = f2b((xv.w-mu)*rstd*g.w + b.w);
  ((ushort4*)(out + (size_t)row*CH))[tid] = o;
}

// ---------------- gemm128: 128x128 tile, BK=32, dbuf LDS = 32KB -> 4 blocks/CU.
// 2-phase loop (STAGE next buf; ds_read+MFMA cur; ONE __syncthreads) — the
// vmcnt(0) drain at the barrier hides under the 3 other resident blocks.
// R6: K-loop unrolled x2 with COMPILE-TIME buffer bases (no dynamic cur)
// and swizzled LDS read offsets hoisted out of the loop — cuts per-iter VALU.
// Barrier placement is instruction-identical to the R4 loop.
// Swizzle for 64B rows: slot s of row r holds global 16B chunk s^((r>>1)&3);
// ds_read_b128 by 16 consecutive rows then covers each bank exactly 2x (free).
// OMODE: 0 = fp32 out, 1 = bf16 out, 3 = fused QKV epilogue (q/k token-major,
// v pi-permuted transposed). OMODE 1/3 stage wave's 64x64 bf16 tile in LDS
// scratch then store coalesced 16B.
template<int BIAS,int GELU,int RES,int OMODE>
__global__ __launch_bounds__(256,4) void gemm128(const unsigned short* __restrict__ A,
    const unsigned short* __restrict__ Bt, const float* __restrict__ bias,
    const float* __restrict__ resid, float* __restrict__ outF,
    unsigned short* __restrict__ outB, unsigned short* __restrict__ outK,
    unsigned short* __restrict__ outV, int M, int Nn, int K)
{
  __shared__ __align__(16) char lds[32768];   // A dbuf 2x8KB @0 | B dbuf 2x8KB @16K
  const int tid = threadIdx.x;
  const int w = tid >> 6, lane = tid & 63;
  const int quad = lane >> 4, l16 = lane & 15;
  const unsigned Wid = xcd_chunk(blockIdx.y*gridDim.x + blockIdx.x,
                                 gridDim.x*gridDim.y);
  const int bx = Wid % gridDim.x, by = Wid / gridDim.x;
  const int m0 = by*128, n0 = bx*128;
  const int wm = (w >> 1)*64, wn = (w & 1)*64;
  f32x4 acc[4][4] = {};
  const int nt = K >> 5;                       // K multiple of 64 -> nt even

  // staging: 8 chunks of 1KB per operand per buffer; this thread owns chunks
  // {w*2, w*2+1}. lane l -> row ci*16 + (l>>2), slot l&3, global chunk
  // g = (l&3) ^ ((row>>1)&3).
  const int ci0 = w*2, ci1 = w*2 + 1;
  const int ra0 = ci0*16 + (lane >> 2);
  const int ra1 = ra0 + 16;
  const int ga0 = (lane & 3) ^ ((ra0 >> 1) & 3);
  const int ga1 = (lane & 3) ^ ((ra1 >> 1) & 3);
  const unsigned short* aS0 = A  + (size_t)(m0 + ra0)*K + ga0*8;
  const unsigned short* aS1 = A  + (size_t)(m0 + ra1)*K + ga1*8;
  const unsigned short* bS0 = Bt + (size_t)(n0 + ra0)*K + ga0*8;
  const unsigned short* bS1 = Bt + (size_t)(n0 + ra1)*K + ga1*8;

  auto STAGE = [&](int buf){
    char* Ad = lds + buf*8192;
    char* Bd = lds + 16384 + buf*8192;
    gl2lds16(aS0, Ad + ci0*1024);
    gl2lds16(aS1, Ad + ci1*1024);
    gl2lds16(bS0, Bd + ci0*1024);
    gl2lds16(bS1, Bd + ci1*1024);
    aS0 += 32; aS1 += 32; bS0 += 32; bS1 += 32;
  };

  // hoisted swizzled LDS read offsets (loop-invariant)
  int aoff[4], boff[4];
  #pragma unroll
  for (int mi = 0; mi < 4; mi++){
    const int r = wm + mi*16 + l16;
    aoff[mi] = r*32 + ((quad ^ ((r >> 1) & 3))*8);
  }
  #pragma unroll
  for (int nj = 0; nj < 4; nj++){
    const int r = wn + nj*16 + l16;
    boff[nj] = r*32 + ((quad ^ ((r >> 1) & 3))*8);
  }

  auto COMPUTE = [&](const unsigned short* Ac, const unsigned short* Bc){
    bf16x8 af[4], bfr[4];
    #pragma unroll
    for (int mi = 0; mi < 4; mi++) af[mi]  = *(const bf16x8*)(Ac + aoff[mi]);
    #pragma unroll
    for (int nj = 0; nj < 4; nj++) bfr[nj] = *(const bf16x8*)(Bc + boff[nj]);
    #pragma unroll
    for (int mi = 0; mi < 4; mi++)
      #pragma unroll
      for (int nj = 0; nj < 4; nj++)
        acc[mi][nj] = MFMA16(af[mi], bfr[nj], acc[mi][nj]);
  };
  const unsigned short* A0 = (const unsigned short*)(lds);
  const unsigned short* A1 = (const unsigned short*)(lds + 8192);
  const unsigned short* B0 = (const unsigned short*)(lds + 16384);
  const unsigned short* B1 = (const unsigned short*)(lds + 24576);

  STAGE(0);                     // tile 0
  __syncthreads();
  for (int t2 = 0; t2 < (nt >> 1) - 1; t2++){
    STAGE(1);                   // tile 2*t2+1
    COMPUTE(A0, B0);            // tile 2*t2
    __syncthreads();
    STAGE(0);                   // tile 2*t2+2
    COMPUTE(A1, B1);            // tile 2*t2+1
    __syncthreads();
  }
  STAGE(1);                     // tile nt-1
  COMPUTE(A0, B0);              // tile nt-2
  __syncthreads();
  COMPUTE(A1, B1);              // tile nt-1
  __syncthreads();              // protect epilogue LDS scratch reuse

  // epilogue: C/D layout col = l16, row = quad*4 + reg
  const int colb = n0 + wn;          // 64-aligned
  const int row0 = m0 + wm;          // 64-aligned
  if (OMODE == 1 || OMODE == 3){
    unsigned short* scr = (unsigned short*)lds + w*4096;   // 8KB per wave
    const int cg = (OMODE == 3) ? (colb >> 10) : 0;
    #pragma unroll
    for (int nj = 0; nj < 4; nj++){
      const int col = colb + nj*16 + l16;
      const float bv = BIAS ? bias[col] : 0.f;
      #pragma unroll
      for (int mi = 0; mi < 4; mi++){
        #pragma unroll
        for (int r = 0; r < 4; r++){
          const int rl = mi*16 + quad*4 + r;     // local row 0..63
          float v = acc[mi][nj][r] + bv;
          if (GELU) v = 0.5f*v*(1.f + erff(v*0.70710678118654752f));
          if (RES)  v += resid[(size_t)(row0 + rl)*Nn + col];
          const unsigned short b16 = f2b(v);
          if (OMODE == 3 && cg == 2){
            // V: scratch [64 d][64 tok], tokens pi-permuted
            const int d = nj*16 + l16;
            scr[d*64 + (((rl & 15) << 2) | (rl >> 4))] = b16;
          } else {
            scr[rl*64 + nj*16 + l16] = b16;
          }
        }
      }
    }
    const int sl = (lane & 7)*8;
    #pragma unroll
    for (int j = 0; j < 8; j++){
      const int rr = j*8 + (lane >> 3);
      const bf16x8 vv = *(const bf16x8*)(scr + rr*64 + sl);
      if (OMODE == 1){
        *(bf16x8*)(outB + (size_t)(row0 + rr)*Nn + colb + sl) = vv;
      } else {
        if (cg == 0)
          *(bf16x8*)(outB + (size_t)(row0 + rr)*CH + (colb & (CH-1)) + sl) = vv;
        else if (cg == 1)
          *(bf16x8*)(outK + (size_t)(row0 + rr)*CH + (colb & (CH-1)) + sl) = vv;
        else {
          const int bb = row0 >> 11;
          const int hh = (colb & (CH-1)) >> 6;
          *(bf16x8*)(outV + ((size_t)((bb*NH + hh)*HD) + rr)*SEQ
                          + (row0 & (SEQ-1)) + sl) = vv;
        }
      }
    }
    return;
  }
  // OMODE 0: fp32 direct
  #pragma unroll
  for (int nj = 0; nj < 4; nj++){
    const int col = colb + nj*16 + l16;
    const float bv = BIAS ? bias[col] : 0.f;
    #pragma unroll
    for (int mi = 0; mi < 4; mi++){
      #pragma unroll
      for (int r = 0; r < 4; r++){
        const int row = row0 + mi*16 + quad*4 + r;
        float v = acc[mi][nj][r] + bv;
        if (GELU) v = 0.5f*v*(1.f + erff(v*0.70710678118654752f));
        if (RES)  v += resid[(size_t)row*Nn + col];
        outF[(size_t)row*Nn + col] = v;
      }
    }
  }
}

// ---------------- 128-row-tile GEMM, BK=64 dbuf (proven R2 config; Wp + W2)
template<int BNT,int BIAS,int GELU,int RES,int OMODE,int SPLITK>
__global__ __launch_bounds__(256,2) void gemm_bt(const unsigned short* __restrict__ A,
    const unsigned short* __restrict__ Bt, const float* __restrict__ bias,
    const float* __restrict__ resid, float* __restrict__ outF,
    unsigned short* __restrict__ outB, unsigned short* __restrict__ outK,
    unsigned short* __restrict__ outV, int M, int Nn, int K)
{
  constexpr int MI  = (BNT==128) ? 4 : 2;
  constexpr int BCH = (BNT==128) ? 4 : 2;
  constexpr int ABYTES = 128*64*2;
  constexpr int BBYTES = BNT*64*2;
  __shared__ __align__(16) char lds[2*ABYTES + 2*BBYTES];
  const int tid = threadIdx.x;
  const int w = tid >> 6, lane = tid & 63;
  const int quad = lane >> 4, l16 = lane & 15;
  const unsigned Wid = xcd_chunk(blockIdx.y*gridDim.x + blockIdx.x,
                                 gridDim.x*gridDim.y);
  const int bx = Wid % gridDim.x, by = Wid / gridDim.x;
  const int m0 = by*128, n0 = bx*BNT;
  const int wm = (BNT==128) ? (w >> 1)*64 : w*32;
  const int wn = (BNT==128) ? (w & 1)*64 : 0;
  const int srow = lane >> 3, sslot = lane & 7;
  f32x4 acc[MI][4] = {};
  const int kseg = SPLITK > 1 ? K / SPLITK : K;
  const int kBeg = SPLITK > 1 ? blockIdx.z * kseg : 0;
  const int nsteps = kseg >> 6;

  auto STAGE = [&](int buf, int k0){
    char* Ad = lds + buf*ABYTES;
    char* Bd = lds + 2*ABYTES + buf*BBYTES;
    #pragma unroll
    for (int i = 0; i < 4; i++){
      const int rb = (w*4 + i)*8;
      const int r = rb + srow;
      const int c = sslot ^ (r & 7);
      gl2lds16(A + (size_t)(m0 + r)*K + k0 + c*8, Ad + rb*128);
    }
    #pragma unroll
    for (int i = 0; i < BCH; i++){
      const int rb = (w*BCH + i)*8;
      const int r = rb + srow;
      const int c = sslot ^ (r & 7);
      gl2lds16(Bt + (size_t)(n0 + r)*K + k0 + c*8, Bd + rb*128);
    }
  };

  STAGE(0, kBeg);
  __syncthreads();
  for (int t = 0; t < nsteps; t++){
    const int cur = t & 1;
    if (t + 1 < nsteps) STAGE(cur ^ 1, kBeg + (t+1)*64);
    const unsigned short* Ac = (const unsigned short*)(lds + cur*ABYTES);
    const unsigned short* Bc = (const unsigned short*)(lds + 2*ABYTES + cur*BBYTES);
    #pragma unroll
    for (int kc = 0; kc < 2; kc++){
      bf16x8 af[MI], bfr[4];
      #pragma unroll
      for (int mi = 0; mi < MI; mi++){
        const int r = wm + mi*16 + l16;
        af[mi] = *(const bf16x8*)(Ac + r*64 + (((kc*4 + quad) ^ (r & 7))*8));
      }
      #pragma unroll
      for (int nj = 0; nj < 4; nj++){
        const int r = wn + nj*16 + l16;
        bfr[nj] = *(const bf16x8*)(Bc + r*64 + (((kc*4 + quad) ^ (r & 7))*8));
      }
      #pragma unroll
      for (int mi = 0; mi < MI; mi++)
        #pragma unroll
        for (int nj = 0; nj < 4; nj++)
          acc[mi][nj] = MFMA16(af[mi], bfr[nj], acc[mi][nj]);
    }
    __syncthreads();
  }

  #pragma unroll
  for (int nj = 0; nj < 4; nj++){
    const int col = n0 + wn + nj*16 + l16;
    const float bv = BIAS ? bias[col] : 0.f;
    #pragma unroll
    for (int mi = 0; mi < MI; mi++){
      #pragma unroll
      for (int r = 0; r < 4; r++){
        const int row = m0 + wm + mi*16 + quad*4 + r;
        float v = acc[mi][nj][r];
        if (SPLITK > 1){
          if (blockIdx.z == 0){
            if (BIAS) v += bias[col];
            if (RES)  v += resid[(size_t)row*Nn + col];
          }
          atomicAdd(&outF[(size_t)row*Nn + col], v);
          continue;
        }
        v += bv;
        if (GELU) v = 0.5f*v*(1.f + erff(v*0.70710678118654752f));
        if (RES)  v += resid[(size_t)row*Nn + col];
        if (OMODE == 0) outF[(size_t)row*Nn + col] = v;
        else outB[(size_t)row*Nn + col] = f2b(v);
      }
    }
  }
}

// ---------------- fused attention, no-max softmax (scores tiny; log2e folded into Wq)
// q,k token-major bf16; vt [bh][d][kv-pi-permuted] bf16.
// Block = one (b,h) x 128 Q rows; 4 waves = (wq: q-half of 64 rows) x (wk: kv-half).
// Grid XCD-chunk-swizzled: each XCD owns 4 heads (2MB K+V, L2-resident).
// R6: T5 setprio(1) around the QK and PV MFMA clusters (wq/wk role-split
// regime; m191 within-probe +4-7%).
__global__ __launch_bounds__(256,2) void attn_kernel(const unsigned short* __restrict__ q,
    const unsigned short* __restrict__ k, const unsigned short* __restrict__ vt,
    unsigned short* __restrict__ y)
{
  __shared__ __align__(16) unsigned short Kl[2][64*64];
  __shared__ __align__(16) unsigned short Vl[2][64*64];
  __shared__ __align__(16) unsigned short Pp[4][64*68];
  const int tid = threadIdx.x;
  const int w = tid >> 6, lane = tid & 63;
  const int wq = w & 1, wk = w >> 1;
  const int quad = lane >> 4, l16 = lane & 15;
  const unsigned Wid = xcd_chunk(blockIdx.y*gridDim.x + blockIdx.x,
                                 gridDim.x*gridDim.y);
  const int qt = Wid & 15, bh = Wid >> 4;
  const int b = bh >> 4, h = bh & 15;
  const size_t tb  = ((size_t)b*SEQ)*CH + h*HD;
  const size_t vb_ = (size_t)bh*HD*SEQ;
  const int qr0 = qt*128 + wq*64;

  bf16x8 qf[4][2];
  #pragma unroll
  for (int mi = 0; mi < 4; mi++)
    #pragma unroll
    for (int kc = 0; kc < 2; kc++)
      qf[mi][kc] = *(const bf16x8*)(q + tb + (size_t)(qr0 + mi*16 + l16)*CH + kc*32 + quad*8);

  float sacc[4][4];
  f32x4 o[4][4] = {};
  #pragma unroll
  for (int mi = 0; mi < 4; mi++)
    #pragma unroll
    for (int r = 0; r < 4; r++) sacc[mi][r] = 0.f;

  for (int t = 0; t < 16; t++){
    const int kv0 = wk*1024 + t*64;
    __syncthreads();
    #pragma unroll
    for (int i = 0; i < 8; i++){
      const int r = i*8 + (lane >> 3);
      const int c = (lane & 7) ^ (r & 7);
      if (wq == 0)
        gl2lds16(k  + tb  + (size_t)(kv0 + r)*CH + c*8, (char*)&Kl[wk][0] + i*1024);
      else
        gl2lds16(vt + vb_ + (size_t)r*SEQ + kv0 + c*8, (char*)&Vl[wk][0] + i*1024);
    }
    __syncthreads();

    f32x4 s[4][4] = {};
    __builtin_amdgcn_s_setprio(1);
    #pragma unroll
    for (int kc = 0; kc < 2; kc++){
      #pragma unroll
      for (int nj = 0; nj < 4; nj++){
        bf16x8 kf = *(const bf16x8*)(&Kl[wk][0] + (nj*16 + l16)*64 + (((kc*4 + quad) ^ (l16 & 7))*8));
        #pragma unroll
        for (int mi = 0; mi < 4; mi++)
          s[mi][nj] = MFMA16(qf[mi][kc], kf, s[mi][nj]);
      }
    }
    __builtin_amdgcn_s_setprio(0);
    #pragma unroll
    for (int mi = 0; mi < 4; mi++){
      #pragma unroll
      for (int r = 0; r < 4; r++){
        const float p0 = fexp2(s[mi][0][r]);
        const float p1 = fexp2(s[mi][1][r]);
        const float p2 = fexp2(s[mi][2][r]);
        const float p3 = fexp2(s[mi][3][r]);
        sacc[mi][r] += (p0 + p1) + (p2 + p3);
        uint2 pk;
        pk.x = pk2(p0, p1);
        pk.y = pk2(p2, p3);
        const int prow = mi*16 + quad*4 + r;
        *(uint2*)(&Pp[w][prow*68 + l16*4]) = pk;
      }
    }
    __builtin_amdgcn_s_setprio(1);
    #pragma unroll
    for (int kc = 0; kc < 2; kc++){
      bf16x8 pa[4];
      #pragma unroll
      for (int mi = 0; mi < 4; mi++)
        pa[mi] = *(const bf16x8*)(&Pp[w][(mi*16 + l16)*68 + kc*32 + quad*8]);
      #pragma unroll
      for (int nd = 0; nd < 4; nd++){
        bf16x8 vf = *(const bf16x8*)(&Vl[wk][0] + (nd*16 + l16)*64 + (((kc*4 + quad) ^ (l16 & 7))*8));
        #pragma unroll
        for (int mi = 0; mi < 4; mi++)
          o[mi][nd] = MFMA16(pa[mi], vf, o[mi][nd]);
      }
    }
    __builtin_amdgcn_s_setprio(0);
  }

  __syncthreads();
  float* ob = wq ? (float*)&Vl[0][0] : (float*)&Kl[0][0];
  float* sb = (float*)&Pp[2 + wq][0];
  if (wk == 1){
    #pragma unroll
    for (int mi = 0; mi < 4; mi++)
      #pragma unroll
      for (int nd = 0; nd < 4; nd++)
        #pragma unroll
        for (int r = 0; r < 4; r++){
          const int idx = (mi*4 + nd)*4 + r;
          ob[lane*64 + ((idx + lane) & 63)] = o[mi][nd][r];
        }
    #pragma unroll
    for (int mi = 0; mi < 4; mi++)
      #pragma unroll
      for (int r = 0; r < 4; r++)
        sb[lane*16 + ((mi*4 + r + lane) & 15)] = sacc[mi][r];
  }
  __syncthreads();
  if (wk == 0){
    #pragma unroll
    for (int mi = 0; mi < 4; mi++)
      #pragma unroll
      for (int nd = 0; nd < 4; nd++)
        #pragma unroll
        for (int r = 0; r < 4; r++){
          const int idx = (mi*4 + nd)*4 + r;
          o[mi][nd][r] += ob[lane*64 + ((idx + lane) & 63)];
        }
    #pragma unroll
    for (int mi = 0; mi < 4; mi++){
      #pragma unroll
      for (int r = 0; r < 4; r++){
        float sum = sacc[mi][r] + sb[lane*16 + ((mi*4 + r + lane) & 15)];
        #pragma unroll
        for (int off = 1; off < 16; off <<= 1) sum += __shfl_xor(sum, off, 64);
        const float inv = 1.f / sum;
        const int qr = qr0 + mi*16 + quad*4 + r;
        #pragma unroll
        for (int nd = 0; nd < 4; nd++)
          y[tb + (size_t)qr*CH + nd*16 + l16] = f2b(o[mi][nd][r]*inv);
      }
    }
  }
}

extern "C" void kernel_launch(void* const* d_in, const int* in_sizes, int n_in,
                              void* d_out, int out_size, void* d_ws, size_t ws_size,
                              hipStream_t stream)
{
  (void)in_sizes; (void)n_in; (void)out_size; (void)ws_size;
  const float* x   = (const float*)d_in[0];
  const float* Wq  = (const float*)d_in[1];
  const float* Wk  = (const float*)d_in[2];
  const float* Wv  = (const float*)d_in[3];
  const float* Wp  = (const float*)d_in[4];
  const float* bp  = (const float*)d_in[5];
  const float* W1  = (const float*)d_in[6];
  const float* b1  = (const float*)d_in[7];
  const float* W2  = (const float*)d_in[8];
  const float* b2  = (const float*)d_in[9];
  const float* g1  = (const float*)d_in[10];
  const float* be1 = (const float*)d_in[11];
  const float* g2  = (const float*)d_in[12];
  const float* be2 = (const float*)d_in[13];
  float* out = (float*)d_out;
  char* ws = (char*)d_ws;
  const size_t MB = 1024*1024;
  unsigned short* wq_t = (unsigned short*)(ws +  0*MB);  // stacked QKV^T: rows 0..3071
  unsigned short* wk_t = (unsigned short*)(ws +  2*MB);
  unsigned short* wv_t = (unsigned short*)(ws +  4*MB);
  unsigned short* wp_t = (unsigned short*)(ws +  6*MB);
  unsigned short* w1_t = (unsigned short*)(ws +  8*MB);
  unsigned short* w2_t = (unsigned short*)(ws + 16*MB);
  unsigned short* xn   = (unsigned short*)(ws + 24*MB);
  unsigned short* qb   = (unsigned short*)(ws + 32*MB);
  unsigned short* kb   = (unsigned short*)(ws + 40*MB);
  unsigned short* vtb  = (unsigned short*)(ws + 48*MB);
  unsigned short* yb   = (unsigned short*)(ws + 56*MB);
  float*          x2   = (float*)         (ws + 64*MB);
  unsigned short* xn2  = (unsigned short*)(ws + 80*MB);
  unsigned short* hb   = (unsigned short*)(ws + 88*MB);

  // all six weight transposes in ONE launch (head scale * log2e folded into Wq)
  transpose_all<<<dim3(3072),256,0,stream>>>(Wq, Wk, Wv, Wp, W1, W2,
      wq_t, wk_t, wv_t, wp_t, w1_t, w2_t);

  ln_kernel<<<BN,256,0,stream>>>(x, g1, be1, xn);
  // fused QKV: Bt = stacked [3072][1024] starting at wq_t
  gemm128<0,0,0,3><<<dim3(24,32),256,0,stream>>>(xn, wq_t, nullptr, nullptr,
      nullptr, qb, kb, vtb, BN, 3072, CH);
  attn_kernel<<<dim3(16,32),256,0,stream>>>(qb, kb, vtb, yb);
  gemm_bt<64,1,0,1,0,0><<<dim3(16,32),256,0,stream>>>(yb, wp_t, bp, x, x2,
      nullptr, nullptr, nullptr, BN, CH, CH);
  ln_kernel<<<BN,256,0,stream>>>(x2, g2, be2, xn2);
  gemm128<1,1,0,1><<<dim3(32,32),256,0,stream>>>(xn2, w1_t, b1, nullptr, nullptr,
      hb, nullptr, nullptr, BN, FF, CH);
  // W2: single pass (no split-K, no memset, no atomics)
  gemm_bt<64,1,0,1,0,0><<<dim3(16,32),256,0,stream>>>(hb, w2_t, b2, x2, out,
      nullptr, nullptr, nullptr, BN, CH, FF);
}